// Round 7
// baseline (444.806 us; speedup 1.0000x reference)
//
#include <hip/hip_runtime.h>

#define IN_CH  256
#define HCC    256   // HEADS*OUT_CH
#define HEADS  4
#define OUTC   64
#define NEG_SLOPE 0.2f

#define NSH    8     // dst-range shards == XCD count (blockIdx%8 ~ XCD)
#define CAP    256   // LDS FIFO entries per shard (flush chunk = 1KB)
#define SUBG2  64    // blocks per shard in deg2/scatter2

using short8v = __attribute__((ext_vector_type(8))) short;
using f32x4   = __attribute__((ext_vector_type(4))) float;

__device__ __forceinline__ unsigned short f2bf(float f) {
    unsigned u = __float_as_uint(f);
    unsigned r = (u + 0x7fffu + ((u >> 16) & 1u)) >> 16;  // RNE
    return (unsigned short)r;
}
__device__ __forceinline__ float bf2f(unsigned short b) {
    return __uint_as_float((unsigned)b << 16);
}
__device__ __forceinline__ int shard_of(int dst, unsigned M) {
    unsigned s = (unsigned)(((unsigned long long)(unsigned)dst * M) >> 32);
    return (s >= NSH) ? (NSH - 1) : (int)s;
}

// ---------------------------------------------------------------------------
// Kernel 0: W [K=256][N=256] fp32 -> WT [N][K] bf16 (tiny, one-time)
// ---------------------------------------------------------------------------
__global__ void k_wt(const float* __restrict__ W,
                     unsigned short* __restrict__ WT) {
    int n = blockIdx.x;
    int k = threadIdx.x;
    WT[n * IN_CH + k] = f2bf(W[(size_t)k * HCC + n]);
}

// ---------------------------------------------------------------------------
// Kernel 1: x_lin = X @ W via bf16 MFMA, BM=64, BN=256, BK=64.
// B fragments loaded DIRECT from global (W = 128KB, L2-resident on every
// XCD) -> no B LDS tile: LDS 46->9KB, occupancy up, staging halved.
// Attention logit dots fused in epilogue (wave w == head w).
// ---------------------------------------------------------------------------
__global__ __launch_bounds__(256) void k_gemm(const float* __restrict__ X,
                                              const unsigned short* __restrict__ WT,
                                              const float* __restrict__ ASRC,
                                              const float* __restrict__ ADST,
                                              unsigned short* __restrict__ XLB,
                                              float* __restrict__ a_s,
                                              float* __restrict__ a_d,
                                              int N) {
    __shared__ unsigned short Ats[64][72];   // [m][k]
    const int tid = threadIdx.x;
    const int lane = tid & 63;
    const int wid = tid >> 6;
    const int m0 = blockIdx.x * 64;
    const int r16 = lane & 15;
    const int g = lane >> 4;

    // B row pointers for this lane's 4 n-fragments (rows of WT)
    const unsigned short* bptr[4];
#pragma unroll
    for (int n = 0; n < 4; ++n)
        bptr[n] = WT + (size_t)(wid * 64 + n * 16 + r16) * IN_CH;

    f32x4 acc[4][4];
    const f32x4 z = {0.f, 0.f, 0.f, 0.f};
#pragma unroll
    for (int m = 0; m < 4; ++m)
#pragma unroll
        for (int n = 0; n < 4; ++n) acc[m][n] = z;

    for (int kb = 0; kb < IN_CH; kb += 64) {
        // stage A: 64 rows x 64 k, fp32 -> bf16
#pragma unroll
        for (int it = 0; it < 4; ++it) {
            int v = tid + 256 * it;
            int row = v >> 4;
            int c4 = (v & 15) << 2;
            int gr = m0 + row;
            float4 av = make_float4(0.f, 0.f, 0.f, 0.f);
            if (gr < N) av = *(const float4*)(X + (size_t)gr * IN_CH + kb + c4);
            ushort4 ab;
            ab.x = f2bf(av.x); ab.y = f2bf(av.y);
            ab.z = f2bf(av.z); ab.w = f2bf(av.w);
            *(ushort4*)&Ats[row][c4] = ab;
        }
        __syncthreads();
#pragma unroll
        for (int ks = 0; ks < 2; ++ks) {
            short8v af[4], bf[4];
#pragma unroll
            for (int n = 0; n < 4; ++n)
                bf[n] = *(const short8v*)(bptr[n] + kb + ks * 32 + g * 8);
#pragma unroll
            for (int m = 0; m < 4; ++m)
                af[m] = *(const short8v*)&Ats[m * 16 + r16][ks * 32 + g * 8];
#pragma unroll
            for (int m = 0; m < 4; ++m)
#pragma unroll
                for (int n = 0; n < 4; ++n)
                    acc[m][n] = __builtin_amdgcn_mfma_f32_16x16x32_bf16(
                        af[m], bf[n], acc[m][n], 0, 0, 0);
        }
        __syncthreads();
    }

    const int h = wid;
    float asc[4], adc[4];
#pragma unroll
    for (int n = 0; n < 4; ++n) {
        asc[n] = ASRC[h * OUTC + n * 16 + r16];
        adc[n] = ADST[h * OUTC + n * 16 + r16];
    }

    // epilogue: D frag layout col=lane&15, row=(lane>>4)*4+j  [m89-verified]
#pragma unroll
    for (int m = 0; m < 4; ++m) {
#pragma unroll
        for (int j = 0; j < 4; ++j) {
            int row = m0 + m * 16 + g * 4 + j;
            float ds = 0.f, dd = 0.f;
#pragma unroll
            for (int n = 0; n < 4; ++n) {
                ds = fmaf(acc[m][n][j], asc[n], ds);
                dd = fmaf(acc[m][n][j], adc[n], dd);
            }
#pragma unroll
            for (int o = 1; o < 16; o <<= 1) {
                ds += __shfl_xor(ds, o);
                dd += __shfl_xor(dd, o);
            }
            if (row < N) {
                if (r16 == 0) {
                    a_s[(size_t)row * HEADS + h] = ds;
                    a_d[(size_t)row * HEADS + h] = dd;
                }
#pragma unroll
                for (int n = 0; n < 4; ++n) {
                    int col = wid * 64 + n * 16 + r16;
                    XLB[(size_t)row * HCC + col] = f2bf(acc[m][n][j]);
                }
            }
        }
    }
}

// ---------------------------------------------------------------------------
// CSR build v3: single-pass partition into NSH dst-range shards, then
// XCD-affine deg/scatter over the (small) partitions.
// ---------------------------------------------------------------------------

// shard counts
__global__ __launch_bounds__(256) void k_pcount(const int* __restrict__ ei,
                                                int* __restrict__ pcnt,
                                                int E, unsigned M) {
    __shared__ int hcnt[NSH];
    int t = threadIdx.x;
    if (t < NSH) hcnt[t] = 0;
    __syncthreads();
    for (int i = blockIdx.x * 256 + t; i < E; i += gridDim.x * 256)
        atomicAdd(&hcnt[shard_of(ei[E + i], M)], 1);
    __syncthreads();
    if (t < NSH && hcnt[t]) atomicAdd(&pcnt[t], hcnt[t]);
}

// tiny scan: pbase/ptail
__global__ void k_pscan(const int* __restrict__ pcnt, int* __restrict__ pbase,
                        int* __restrict__ ptail) {
    if (threadIdx.x == 0) {
        int run = 0;
        for (int s = 0; s < NSH; ++s) {
            pbase[s] = run;
            ptail[s] = run;
            run += pcnt[s];
        }
        pbase[NSH] = run;
    }
}

// partition edges: LDS FIFO per shard, flush full 1KB chunks (coalesced, one
// global atomic per chunk). pack = (dst_local << 18) | src.
__global__ __launch_bounds__(256) void k_part(const int* __restrict__ ei,
                                              int* __restrict__ ptail,
                                              unsigned* __restrict__ pedges,
                                              int E, unsigned M, int rng) {
    __shared__ unsigned buf[NSH][CAP];
    __shared__ int lcnt[NSH];
    __shared__ int fbase[NSH];
    __shared__ unsigned flags;
    int t = threadIdx.x;
    if (t < NSH) lcnt[t] = 0;
    __syncthreads();

    for (int base = blockIdx.x * 256; base < E; base += gridDim.x * 256) {
        int i = base + t;
        bool valid = (i < E);
        unsigned pk = 0;
        int s = 0;
        if (valid) {
            int src = ei[i];
            int dst = ei[E + i];
            s = shard_of(dst, M);
            pk = ((unsigned)(dst - s * rng) << 18) | (unsigned)src;
        }
        bool placed = !valid;
        while (true) {
            if (t == 0) flags = 0;
            __syncthreads();
            if (!placed) {
                int pos = atomicAdd(&lcnt[s], 1);
                if (pos < CAP) {
                    buf[s][pos] = pk;
                    placed = true;
                }
            }
            if (!placed) atomicOr(&flags, 1u << 31);
            __syncthreads();
            if (t < NSH && lcnt[t] >= CAP) {
                atomicOr(&flags, 1u << t);
                fbase[t] = atomicAdd(&ptail[t], CAP);
            }
            __syncthreads();
            unsigned fm = flags;
#pragma unroll
            for (int sf = 0; sf < NSH; ++sf)
                if (fm & (1u << sf)) pedges[fbase[sf] + t] = buf[sf][t];
            __syncthreads();
            if (t < NSH && (fm & (1u << t))) lcnt[t] = 0;
            if (!(fm & (1u << 31))) break;
            __syncthreads();
        }
        __syncthreads();
    }

    // drain residuals
    for (int sf = 0; sf < NSH; ++sf) {
        int c = lcnt[sf];
        if (c > 0) {
            if (t == 0) fbase[sf] = atomicAdd(&ptail[sf], c);
            __syncthreads();
            if (t < c) pedges[fbase[sf] + t] = buf[sf][t];
        }
    }
}

// deg init = 1 (self-loop)
__global__ void k_dinit(int* __restrict__ deg, int N) {
    int i = blockIdx.x * 256 + threadIdx.x;
    if (i < N) deg[i] = 1;
}

// degree histogram over partitions; blockIdx%NSH -> shard -> XCD-local atomics
__global__ __launch_bounds__(256) void k_deg2(const int* __restrict__ pbase,
                                              const unsigned* __restrict__ pedges,
                                              int* __restrict__ deg, int rng) {
    int s = blockIdx.x & (NSH - 1);
    int sub = blockIdx.x >> 3;
    int p0 = pbase[s];
    int cnt = pbase[s + 1] - p0;
    int lo = s * rng;
    for (int j = sub * 256 + threadIdx.x; j < cnt; j += SUBG2 * 256)
        atomicAdd(&deg[lo + (pedges[p0 + j] >> 18)], 1);
}

__global__ void k_scan1(const int* __restrict__ in, int* __restrict__ sp,
                        int* __restrict__ bsum, int N) {
    __shared__ int s[256];
    int t = threadIdx.x;
    int i = blockIdx.x * 256 + t;
    int v = (i < N) ? in[i] : 0;
    s[t] = v;
    __syncthreads();
    for (int off = 1; off < 256; off <<= 1) {
        int x = (t >= off) ? s[t - off] : 0;
        __syncthreads();
        s[t] += x;
        __syncthreads();
    }
    if (i < N) sp[i] = s[t];
    if (t == 255) bsum[blockIdx.x] = s[255];
}

__global__ void k_scan2(const int* __restrict__ bsum, int* __restrict__ binc,
                        int nb) {
    __shared__ int s[512];
    int t = threadIdx.x;
    s[t] = (t < nb) ? bsum[t] : 0;
    __syncthreads();
    for (int off = 1; off < 512; off <<= 1) {
        int x = (t >= off) ? s[t - off] : 0;
        __syncthreads();
        s[t] += x;
        __syncthreads();
    }
    binc[t] = s[t];
}

// writes rowptr AND fill (saves the d2d memcpy)
__global__ void k_scan3(const int* __restrict__ sp,
                        const int* __restrict__ binc,
                        int* __restrict__ rowptr, int* __restrict__ fill,
                        int N) {
    int b = blockIdx.x;
    int i = b * 256 + threadIdx.x;
    if (i >= N) return;
    int off = (b > 0) ? binc[b - 1] : 0;
    int v = sp[i] + off;
    rowptr[i + 1] = v;
    if (i + 1 < N) fill[i + 1] = v;
    if (i == 0) {
        rowptr[0] = 0;
        fill[0] = 0;
    }
}

// scatter over partitions (XCD-affine): self-loops + edges
__global__ __launch_bounds__(256) void k_scatter2(const int* __restrict__ pbase,
                                                  const unsigned* __restrict__ pedges,
                                                  int* __restrict__ fill,
                                                  int* __restrict__ eid,
                                                  int rng, int N) {
    int s = blockIdx.x & (NSH - 1);
    int sub = blockIdx.x >> 3;
    int lo = s * rng;
    int hi = lo + rng;
    if (hi > N) hi = N;
    // self-loops for this shard's node range
    for (int n = lo + sub * 256 + threadIdx.x; n < hi; n += SUBG2 * 256) {
        int pos = atomicAdd(&fill[n], 1);
        eid[pos] = n;
    }
    int p0 = pbase[s];
    int cnt = pbase[s + 1] - p0;
    for (int j = sub * 256 + threadIdx.x; j < cnt; j += SUBG2 * 256) {
        unsigned pk = pedges[p0 + j];
        int dst = lo + (int)(pk >> 18);
        int pos = atomicAdd(&fill[dst], 1);
        eid[pos] = (int)(pk & 0x3FFFFu);
    }
}

// ---------------------------------------------------------------------------
// Kernel 3: per-dst softmax + aggregation. One WAVE per node, lane owns 4
// channels. 8-deep edge unroll for gather MLP. No max subtraction (logits
// O(8), fp32 exp safe).
// ---------------------------------------------------------------------------
__global__ __launch_bounds__(256) void k_agg(const int* __restrict__ rowptr,
                                             const int* __restrict__ eid,
                                             const float* __restrict__ a_s,
                                             const float* __restrict__ a_d,
                                             const unsigned short* __restrict__ XLB,
                                             const float* __restrict__ BIAS,
                                             float* __restrict__ OUT, int N) {
    int wid = threadIdx.x >> 6;
    int lane = threadIdx.x & 63;
    int n = blockIdx.x * 4 + wid;
    if (n >= N) return;
    int h = lane >> 4;
    int s0 = rowptr[n];
    int s1 = rowptr[n + 1];
    float adn = a_d[(size_t)n * HEADS + h];
    float s = 0.f;
    float acc0 = 0.f, acc1 = 0.f, acc2 = 0.f, acc3 = 0.f;

    int e = s0;
    for (; e + 8 <= s1; e += 8) {
        int idx[8];
#pragma unroll
        for (int j = 0; j < 8; ++j) idx[j] = eid[e + j];
        float l[8];
#pragma unroll
        for (int j = 0; j < 8; ++j) l[j] = a_s[(size_t)idx[j] * HEADS + h] + adn;
        ushort4 xv[8];
#pragma unroll
        for (int j = 0; j < 8; ++j)
            xv[j] = *(const ushort4*)(XLB + (size_t)idx[j] * HCC + lane * 4);
#pragma unroll
        for (int j = 0; j < 8; ++j) {
            float lj = fmaxf(l[j], NEG_SLOPE * l[j]);
            float p = __expf(lj);
            s += p;
            acc0 = fmaf(p, bf2f(xv[j].x), acc0);
            acc1 = fmaf(p, bf2f(xv[j].y), acc1);
            acc2 = fmaf(p, bf2f(xv[j].z), acc2);
            acc3 = fmaf(p, bf2f(xv[j].w), acc3);
        }
    }
    for (; e + 4 <= s1; e += 4) {
        int idx[4];
#pragma unroll
        for (int j = 0; j < 4; ++j) idx[j] = eid[e + j];
        float l[4];
#pragma unroll
        for (int j = 0; j < 4; ++j) l[j] = a_s[(size_t)idx[j] * HEADS + h] + adn;
        ushort4 xv[4];
#pragma unroll
        for (int j = 0; j < 4; ++j)
            xv[j] = *(const ushort4*)(XLB + (size_t)idx[j] * HCC + lane * 4);
#pragma unroll
        for (int j = 0; j < 4; ++j) {
            float lj = fmaxf(l[j], NEG_SLOPE * l[j]);
            float p = __expf(lj);
            s += p;
            acc0 = fmaf(p, bf2f(xv[j].x), acc0);
            acc1 = fmaf(p, bf2f(xv[j].y), acc1);
            acc2 = fmaf(p, bf2f(xv[j].z), acc2);
            acc3 = fmaf(p, bf2f(xv[j].w), acc3);
        }
    }
    for (; e < s1; ++e) {
        int src = eid[e];
        float l = a_s[(size_t)src * HEADS + h] + adn;
        l = fmaxf(l, NEG_SLOPE * l);
        float p = __expf(l);
        ushort4 xv = *(const ushort4*)(XLB + (size_t)src * HCC + lane * 4);
        s += p;
        acc0 = fmaf(p, bf2f(xv.x), acc0);
        acc1 = fmaf(p, bf2f(xv.y), acc1);
        acc2 = fmaf(p, bf2f(xv.z), acc2);
        acc3 = fmaf(p, bf2f(xv.w), acc3);
    }

    float inv = 1.f / (s + 1e-16f);
    float4 b = *(const float4*)(BIAS + lane * 4);
    float4 o;
    o.x = acc0 * inv + b.x;
    o.y = acc1 * inv + b.y;
    o.z = acc2 * inv + b.z;
    o.w = acc3 * inv + b.w;
    *(float4*)(OUT + (size_t)n * HCC + lane * 4) = o;
}

// ---------------------------------------------------------------------------
extern "C" void kernel_launch(void* const* d_in, const int* in_sizes, int n_in,
                              void* d_out, int out_size, void* d_ws,
                              size_t ws_size, hipStream_t stream) {
    const float* X = (const float*)d_in[0];
    const int* EI = (const int*)d_in[1];
    const float* W = (const float*)d_in[2];
    const float* ASRC = (const float*)d_in[3];
    const float* ADST = (const float*)d_in[4];
    const float* BIAS = (const float*)d_in[5];
    float* OUT = (float*)d_out;

    const int N = in_sizes[0] / IN_CH;
    const int E = in_sizes[1] / 2;
    const int ET = E + N;
    const int rng = (N + NSH - 1) / NSH;
    const unsigned M = (unsigned)(((1ULL << 32) + rng - 1) / (unsigned)rng);

    // workspace layout (all 256B aligned)
    char* w = (char*)d_ws;
    auto align = [](size_t x) { return (x + 255) & ~(size_t)255; };
    size_t o = 0;
    unsigned short* xlb = (unsigned short*)(w + o); o += align((size_t)N * HCC * 2);
    unsigned short* wt = (unsigned short*)(w + o);  o += align((size_t)IN_CH * HCC * 2);
    float* a_s = (float*)(w + o); o += align((size_t)N * HEADS * 4);
    float* a_d = (float*)(w + o); o += align((size_t)N * HEADS * 4);
    int* deg = (int*)(w + o);     o += align((size_t)N * 4);
    int* rowptr = (int*)(w + o);  o += align((size_t)(N + 1) * 4);
    int* fill = (int*)(w + o);    o += align((size_t)N * 4);
    int* eid = (int*)(w + o);     o += align((size_t)ET * 4);
    unsigned* pedges = (unsigned*)(w + o); o += align((size_t)E * 4);
    int* sp = (int*)(w + o);      o += align((size_t)N * 4);
    int* bsum = (int*)(w + o);    o += align(512 * 4);
    int* binc = (int*)(w + o);    o += align(512 * 4);
    int* pcnt = (int*)(w + o);    o += align((NSH + 1) * 4);
    int* pbase = (int*)(w + o);   o += align((NSH + 1) * 4);
    int* ptail = (int*)(w + o);   o += align((NSH + 1) * 4);

    // 0. W -> WT (bf16, transposed)
    k_wt<<<HCC, IN_CH, 0, stream>>>(W, wt);

    // 1. linear projection -> bf16 x_lin + fused attention logits (MFMA)
    k_gemm<<<(N + 63) / 64, 256, 0, stream>>>(X, wt, ASRC, ADST, xlb, a_s,
                                              a_d, N);

    // 2. CSR build: partition once, then XCD-affine deg/scatter
    hipMemsetAsync(pcnt, 0, NSH * 4, stream);
    k_pcount<<<256, 256, 0, stream>>>(EI, pcnt, E, M);
    k_pscan<<<1, 64, 0, stream>>>(pcnt, pbase, ptail);
    k_part<<<256, 256, 0, stream>>>(EI, ptail, pedges, E, M, rng);
    k_dinit<<<(N + 255) / 256, 256, 0, stream>>>(deg, N);
    k_deg2<<<NSH * SUBG2, 256, 0, stream>>>(pbase, pedges, deg, rng);
    int nb1 = (N + 255) / 256;
    k_scan1<<<nb1, 256, 0, stream>>>(deg, sp, bsum, N);
    k_scan2<<<1, 512, 0, stream>>>(bsum, binc, nb1);
    k_scan3<<<nb1, 256, 0, stream>>>(sp, binc, rowptr, fill, N);
    k_scatter2<<<NSH * SUBG2, 256, 0, stream>>>(pbase, pedges, fill, eid,
                                                rng, N);

    // 3. per-dst softmax + weighted aggregation (one wave per node)
    k_agg<<<(N + 3) / 4, 256, 0, stream>>>(rowptr, eid, a_s, a_d, xlb, BIAS,
                                           OUT, N);
}

// Round 8
// 392.600 us; speedup vs baseline: 1.1330x; 1.1330x over previous
//
#include <hip/hip_runtime.h>

#define IN_CH  256
#define HCC    256   // HEADS*OUT_CH
#define HEADS  4
#define OUTC   64
#define NEG_SLOPE 0.2f

#define NSH    8      // dst-range shards == XCD count (blockIdx%8 ~ XCD)
#define NBLK   256    // partition blocks (each owns E/NBLK edge chunk)
#define SUBG2  64     // blocks per shard in deg2/scatter2
#define SRC_BITS 18
#define SRC_MASK 0x3FFFF

using short8v = __attribute__((ext_vector_type(8))) short;
using f32x4   = __attribute__((ext_vector_type(4))) float;

__device__ __forceinline__ unsigned short f2bf(float f) {
    unsigned u = __float_as_uint(f);
    unsigned r = (u + 0x7fffu + ((u >> 16) & 1u)) >> 16;  // RNE
    return (unsigned short)r;
}
__device__ __forceinline__ float bf2f(unsigned short b) {
    return __uint_as_float((unsigned)b << 16);
}
__device__ __forceinline__ int shard_of(int dst, unsigned M) {
    unsigned s = (unsigned)(((unsigned long long)(unsigned)dst * M) >> 32);
    return (s >= NSH) ? (NSH - 1) : (int)s;
}

// ---------------------------------------------------------------------------
// Kernel 0: W [K=256][N=256] fp32 -> WT [N][K] bf16 (tiny, one-time)
// ---------------------------------------------------------------------------
__global__ void k_wt(const float* __restrict__ W,
                     unsigned short* __restrict__ WT) {
    int n = blockIdx.x;
    int k = threadIdx.x;
    WT[n * IN_CH + k] = f2bf(W[(size_t)k * HCC + n]);
}

// ---------------------------------------------------------------------------
// Kernel 1 (R6-exact revert): x_lin = X @ W via bf16 MFMA, BM=64, BN=256,
// BK=64, A and B staged in LDS. Attention logit dots fused in epilogue
// (wave w == head w).
// ---------------------------------------------------------------------------
__global__ __launch_bounds__(256) void k_gemm(const float* __restrict__ X,
                                              const unsigned short* __restrict__ WT,
                                              const float* __restrict__ ASRC,
                                              const float* __restrict__ ADST,
                                              unsigned short* __restrict__ XLB,
                                              float* __restrict__ a_s,
                                              float* __restrict__ a_d,
                                              int N) {
    __shared__ unsigned short Ats[64][72];   // [m][k]
    __shared__ unsigned short Bs[256][72];   // [n][k]
    const int tid = threadIdx.x;
    const int lane = tid & 63;
    const int wid = tid >> 6;
    const int m0 = blockIdx.x * 64;
    const int r16 = lane & 15;
    const int g = lane >> 4;

    f32x4 acc[4][4];
    const f32x4 z = {0.f, 0.f, 0.f, 0.f};
#pragma unroll
    for (int m = 0; m < 4; ++m)
#pragma unroll
        for (int n = 0; n < 4; ++n) acc[m][n] = z;

    for (int kb = 0; kb < IN_CH; kb += 64) {
#pragma unroll
        for (int it = 0; it < 4; ++it) {
            int v = tid + 256 * it;
            int row = v >> 4;
            int c4 = (v & 15) << 2;
            int gr = m0 + row;
            float4 av = make_float4(0.f, 0.f, 0.f, 0.f);
            if (gr < N) av = *(const float4*)(X + (size_t)gr * IN_CH + kb + c4);
            ushort4 ab;
            ab.x = f2bf(av.x); ab.y = f2bf(av.y);
            ab.z = f2bf(av.z); ab.w = f2bf(av.w);
            *(ushort4*)&Ats[row][c4] = ab;
        }
#pragma unroll
        for (int it = 0; it < 8; ++it) {
            int v = tid + 256 * it;
            int brow = v >> 3;
            int c8 = (v & 7) << 3;
            short8v bv = *(const short8v*)(WT + (size_t)brow * IN_CH + kb + c8);
            *(short8v*)&Bs[brow][c8] = bv;
        }
        __syncthreads();
#pragma unroll
        for (int ks = 0; ks < 2; ++ks) {
            short8v af[4], bf[4];
#pragma unroll
            for (int m = 0; m < 4; ++m)
                af[m] = *(const short8v*)&Ats[m * 16 + r16][ks * 32 + g * 8];
#pragma unroll
            for (int n = 0; n < 4; ++n)
                bf[n] = *(const short8v*)&Bs[wid * 64 + n * 16 + r16][ks * 32 + g * 8];
#pragma unroll
            for (int m = 0; m < 4; ++m)
#pragma unroll
                for (int n = 0; n < 4; ++n)
                    acc[m][n] = __builtin_amdgcn_mfma_f32_16x16x32_bf16(
                        af[m], bf[n], acc[m][n], 0, 0, 0);
        }
        __syncthreads();
    }

    const int h = wid;
    float asc[4], adc[4];
#pragma unroll
    for (int n = 0; n < 4; ++n) {
        asc[n] = ASRC[h * OUTC + n * 16 + r16];
        adc[n] = ADST[h * OUTC + n * 16 + r16];
    }

    // epilogue: D frag layout col=lane&15, row=(lane>>4)*4+j  [m89-verified]
#pragma unroll
    for (int m = 0; m < 4; ++m) {
#pragma unroll
        for (int j = 0; j < 4; ++j) {
            int row = m0 + m * 16 + g * 4 + j;
            float ds = 0.f, dd = 0.f;
#pragma unroll
            for (int n = 0; n < 4; ++n) {
                ds = fmaf(acc[m][n][j], asc[n], ds);
                dd = fmaf(acc[m][n][j], adc[n], dd);
            }
#pragma unroll
            for (int o = 1; o < 16; o <<= 1) {
                ds += __shfl_xor(ds, o);
                dd += __shfl_xor(dd, o);
            }
            if (row < N) {
                if (r16 == 0) {
                    a_s[(size_t)row * HEADS + h] = ds;
                    a_d[(size_t)row * HEADS + h] = dd;
                }
#pragma unroll
                for (int n = 0; n < 4; ++n) {
                    int col = wid * 64 + n * 16 + r16;
                    XLB[(size_t)row * HCC + col] = f2bf(acc[m][n][j]);
                }
            }
        }
    }
}

// ---------------------------------------------------------------------------
// CSR build v4: deterministic single-pass partition (no global atomics, no
// barrier protocol), then XCD-affine deg/scatter over the partitions.
// ---------------------------------------------------------------------------

// sweep 1: per-(block,shard) counts via LDS histogram
__global__ __launch_bounds__(256) void k_pcnt(const int* __restrict__ ei,
                                              int* __restrict__ pcnt2d,
                                              int E, unsigned M) {
    __shared__ int h[NSH];
    int t = threadIdx.x;
    if (t < NSH) h[t] = 0;
    __syncthreads();
    int chunk = (E + NBLK - 1) / NBLK;
    int e0 = blockIdx.x * chunk;
    int e1 = e0 + chunk;
    if (e1 > E) e1 = E;
    for (int i = e0 + t; i < e1; i += 256)
        atomicAdd(&h[shard_of(ei[E + i], M)], 1);
    __syncthreads();
    if (t < NSH) pcnt2d[t * NBLK + blockIdx.x] = h[t];
}

// scan of the 2048 (shard-major) counts -> per-(block,shard) bases + pbase
__global__ __launch_bounds__(512) void k_pscan2(const int* __restrict__ pcnt2d,
                                                int* __restrict__ base2d,
                                                int* __restrict__ pbase,
                                                int E) {
    __shared__ int s[512];
    int t = threadIdx.x;
    int c[4];
    int sum = 0;
#pragma unroll
    for (int i = 0; i < 4; ++i) {
        c[i] = pcnt2d[t * 4 + i];
        sum += c[i];
    }
    s[t] = sum;
    __syncthreads();
    for (int off = 1; off < 512; off <<= 1) {
        int x = (t >= off) ? s[t - off] : 0;
        __syncthreads();
        s[t] += x;
        __syncthreads();
    }
    int run = s[t] - sum;  // exclusive
#pragma unroll
    for (int i = 0; i < 4; ++i) {
        int j = t * 4 + i;
        base2d[j] = run;
        if ((j & (NBLK - 1)) == 0) pbase[j / NBLK] = run;
        run += c[i];
    }
    if (t == 0) pbase[NSH] = E;
}

// sweep 2: write packed edges into exact block-private (block,shard) segments
__global__ __launch_bounds__(256) void k_part2(const int* __restrict__ ei,
                                               const int* __restrict__ base2d,
                                               unsigned* __restrict__ pedges,
                                               int E, unsigned M, int rng) {
    __shared__ int cur[NSH];
    int t = threadIdx.x;
    if (t < NSH) cur[t] = base2d[t * NBLK + blockIdx.x];
    __syncthreads();
    int chunk = (E + NBLK - 1) / NBLK;
    int e0 = blockIdx.x * chunk;
    int e1 = e0 + chunk;
    if (e1 > E) e1 = E;
    for (int i = e0 + t; i < e1; i += 256) {
        int src = ei[i];
        int dst = ei[E + i];
        int s = shard_of(dst, M);
        int pos = atomicAdd(&cur[s], 1);  // LDS atomic only
        pedges[pos] = ((unsigned)(dst - s * rng) << SRC_BITS) | (unsigned)src;
    }
}

// deg init = 1 (self-loop)
__global__ void k_dinit(int* __restrict__ deg, int N) {
    int i = blockIdx.x * 256 + threadIdx.x;
    if (i < N) deg[i] = 1;
}

// degree histogram over partitions; blockIdx%NSH -> shard -> XCD-local atomics
__global__ __launch_bounds__(256) void k_deg2(const int* __restrict__ pbase,
                                              const unsigned* __restrict__ pedges,
                                              int* __restrict__ deg, int rng) {
    int s = blockIdx.x & (NSH - 1);
    int sub = blockIdx.x >> 3;
    int p0 = pbase[s];
    int cnt = pbase[s + 1] - p0;
    int lo = s * rng;
    for (int j = sub * 256 + threadIdx.x; j < cnt; j += SUBG2 * 256)
        atomicAdd(&deg[lo + (pedges[p0 + j] >> SRC_BITS)], 1);
}

__global__ void k_scan1(const int* __restrict__ in, int* __restrict__ sp,
                        int* __restrict__ bsum, int N) {
    __shared__ int s[256];
    int t = threadIdx.x;
    int i = blockIdx.x * 256 + t;
    int v = (i < N) ? in[i] : 0;
    s[t] = v;
    __syncthreads();
    for (int off = 1; off < 256; off <<= 1) {
        int x = (t >= off) ? s[t - off] : 0;
        __syncthreads();
        s[t] += x;
        __syncthreads();
    }
    if (i < N) sp[i] = s[t];
    if (t == 255) bsum[blockIdx.x] = s[255];
}

__global__ void k_scan2(const int* __restrict__ bsum, int* __restrict__ binc,
                        int nb) {
    __shared__ int s[512];
    int t = threadIdx.x;
    s[t] = (t < nb) ? bsum[t] : 0;
    __syncthreads();
    for (int off = 1; off < 512; off <<= 1) {
        int x = (t >= off) ? s[t - off] : 0;
        __syncthreads();
        s[t] += x;
        __syncthreads();
    }
    binc[t] = s[t];
}

// writes rowptr AND fill (saves the d2d memcpy)
__global__ void k_scan3(const int* __restrict__ sp,
                        const int* __restrict__ binc,
                        int* __restrict__ rowptr, int* __restrict__ fill,
                        int N) {
    int b = blockIdx.x;
    int i = b * 256 + threadIdx.x;
    if (i >= N) return;
    int off = (b > 0) ? binc[b - 1] : 0;
    int v = sp[i] + off;
    rowptr[i + 1] = v;
    if (i + 1 < N) fill[i + 1] = v;
    if (i == 0) {
        rowptr[0] = 0;
        fill[0] = 0;
    }
}

// scatter over partitions (XCD-affine): self-loops + edges
__global__ __launch_bounds__(256) void k_scatter2(const int* __restrict__ pbase,
                                                  const unsigned* __restrict__ pedges,
                                                  int* __restrict__ fill,
                                                  int* __restrict__ eid,
                                                  int rng, int N) {
    int s = blockIdx.x & (NSH - 1);
    int sub = blockIdx.x >> 3;
    int lo = s * rng;
    int hi = lo + rng;
    if (hi > N) hi = N;
    for (int n = lo + sub * 256 + threadIdx.x; n < hi; n += SUBG2 * 256) {
        int pos = atomicAdd(&fill[n], 1);
        eid[pos] = n;
    }
    int p0 = pbase[s];
    int cnt = pbase[s + 1] - p0;
    for (int j = sub * 256 + threadIdx.x; j < cnt; j += SUBG2 * 256) {
        unsigned pk = pedges[p0 + j];
        int dst = lo + (int)(pk >> SRC_BITS);
        int pos = atomicAdd(&fill[dst], 1);
        eid[pos] = (int)(pk & SRC_MASK);
    }
}

// ---------------------------------------------------------------------------
// Kernel 3: per-dst softmax + aggregation. One WAVE per node, lane owns 4
// channels. 8-deep edge unroll for gather MLP. No max subtraction (logits
// O(8), fp32 exp safe).
// ---------------------------------------------------------------------------
__global__ __launch_bounds__(256) void k_agg(const int* __restrict__ rowptr,
                                             const int* __restrict__ eid,
                                             const float* __restrict__ a_s,
                                             const float* __restrict__ a_d,
                                             const unsigned short* __restrict__ XLB,
                                             const float* __restrict__ BIAS,
                                             float* __restrict__ OUT, int N) {
    int wid = threadIdx.x >> 6;
    int lane = threadIdx.x & 63;
    int n = blockIdx.x * 4 + wid;
    if (n >= N) return;
    int h = lane >> 4;
    int s0 = rowptr[n];
    int s1 = rowptr[n + 1];
    float adn = a_d[(size_t)n * HEADS + h];
    float s = 0.f;
    float acc0 = 0.f, acc1 = 0.f, acc2 = 0.f, acc3 = 0.f;

    int e = s0;
    for (; e + 8 <= s1; e += 8) {
        int idx[8];
#pragma unroll
        for (int j = 0; j < 8; ++j) idx[j] = eid[e + j];
        float l[8];
#pragma unroll
        for (int j = 0; j < 8; ++j) l[j] = a_s[(size_t)idx[j] * HEADS + h] + adn;
        ushort4 xv[8];
#pragma unroll
        for (int j = 0; j < 8; ++j)
            xv[j] = *(const ushort4*)(XLB + (size_t)idx[j] * HCC + lane * 4);
#pragma unroll
        for (int j = 0; j < 8; ++j) {
            float lj = fmaxf(l[j], NEG_SLOPE * l[j]);
            float p = __expf(lj);
            s += p;
            acc0 = fmaf(p, bf2f(xv[j].x), acc0);
            acc1 = fmaf(p, bf2f(xv[j].y), acc1);
            acc2 = fmaf(p, bf2f(xv[j].z), acc2);
            acc3 = fmaf(p, bf2f(xv[j].w), acc3);
        }
    }
    for (; e + 4 <= s1; e += 4) {
        int idx[4];
#pragma unroll
        for (int j = 0; j < 4; ++j) idx[j] = eid[e + j];
        float l[4];
#pragma unroll
        for (int j = 0; j < 4; ++j) l[j] = a_s[(size_t)idx[j] * HEADS + h] + adn;
        ushort4 xv[4];
#pragma unroll
        for (int j = 0; j < 4; ++j)
            xv[j] = *(const ushort4*)(XLB + (size_t)idx[j] * HCC + lane * 4);
#pragma unroll
        for (int j = 0; j < 4; ++j) {
            float lj = fmaxf(l[j], NEG_SLOPE * l[j]);
            float p = __expf(lj);
            s += p;
            acc0 = fmaf(p, bf2f(xv[j].x), acc0);
            acc1 = fmaf(p, bf2f(xv[j].y), acc1);
            acc2 = fmaf(p, bf2f(xv[j].z), acc2);
            acc3 = fmaf(p, bf2f(xv[j].w), acc3);
        }
    }
    for (; e < s1; ++e) {
        int src = eid[e];
        float l = a_s[(size_t)src * HEADS + h] + adn;
        l = fmaxf(l, NEG_SLOPE * l);
        float p = __expf(l);
        ushort4 xv = *(const ushort4*)(XLB + (size_t)src * HCC + lane * 4);
        s += p;
        acc0 = fmaf(p, bf2f(xv.x), acc0);
        acc1 = fmaf(p, bf2f(xv.y), acc1);
        acc2 = fmaf(p, bf2f(xv.z), acc2);
        acc3 = fmaf(p, bf2f(xv.w), acc3);
    }

    float inv = 1.f / (s + 1e-16f);
    float4 b = *(const float4*)(BIAS + lane * 4);
    float4 o;
    o.x = acc0 * inv + b.x;
    o.y = acc1 * inv + b.y;
    o.z = acc2 * inv + b.z;
    o.w = acc3 * inv + b.w;
    *(float4*)(OUT + (size_t)n * HCC + lane * 4) = o;
}

// ---------------------------------------------------------------------------
extern "C" void kernel_launch(void* const* d_in, const int* in_sizes, int n_in,
                              void* d_out, int out_size, void* d_ws,
                              size_t ws_size, hipStream_t stream) {
    const float* X = (const float*)d_in[0];
    const int* EI = (const int*)d_in[1];
    const float* W = (const float*)d_in[2];
    const float* ASRC = (const float*)d_in[3];
    const float* ADST = (const float*)d_in[4];
    const float* BIAS = (const float*)d_in[5];
    float* OUT = (float*)d_out;

    const int N = in_sizes[0] / IN_CH;
    const int E = in_sizes[1] / 2;
    const int ET = E + N;
    const int rng = (N + NSH - 1) / NSH;
    const unsigned M = (unsigned)(((1ULL << 32) + rng - 1) / (unsigned)rng);

    // workspace layout (all 256B aligned)
    char* w = (char*)d_ws;
    auto align = [](size_t x) { return (x + 255) & ~(size_t)255; };
    size_t o = 0;
    unsigned short* xlb = (unsigned short*)(w + o); o += align((size_t)N * HCC * 2);
    unsigned short* wt = (unsigned short*)(w + o);  o += align((size_t)IN_CH * HCC * 2);
    float* a_s = (float*)(w + o); o += align((size_t)N * HEADS * 4);
    float* a_d = (float*)(w + o); o += align((size_t)N * HEADS * 4);
    int* deg = (int*)(w + o);     o += align((size_t)N * 4);
    int* rowptr = (int*)(w + o);  o += align((size_t)(N + 1) * 4);
    int* fill = (int*)(w + o);    o += align((size_t)N * 4);
    int* eid = (int*)(w + o);     o += align((size_t)ET * 4);
    unsigned* pedges = (unsigned*)(w + o); o += align((size_t)E * 4);
    int* sp = (int*)(w + o);      o += align((size_t)N * 4);
    int* bsum = (int*)(w + o);    o += align(512 * 4);
    int* binc = (int*)(w + o);    o += align(512 * 4);
    int* pcnt2d = (int*)(w + o);  o += align((size_t)NSH * NBLK * 4);
    int* base2d = (int*)(w + o);  o += align((size_t)NSH * NBLK * 4);
    int* pbase = (int*)(w + o);   o += align((NSH + 1) * 4);

    // 0. W -> WT (bf16, transposed)
    k_wt<<<HCC, IN_CH, 0, stream>>>(W, wt);

    // 1. linear projection -> bf16 x_lin + fused attention logits (MFMA)
    k_gemm<<<(N + 63) / 64, 256, 0, stream>>>(X, wt, ASRC, ADST, xlb, a_s,
                                              a_d, N);

    // 2. CSR build: deterministic partition, then XCD-affine deg/scatter
    k_pcnt<<<NBLK, 256, 0, stream>>>(EI, pcnt2d, E, M);
    k_pscan2<<<1, 512, 0, stream>>>(pcnt2d, base2d, pbase, E);
    k_part2<<<NBLK, 256, 0, stream>>>(EI, base2d, pedges, E, M, rng);
    k_dinit<<<(N + 255) / 256, 256, 0, stream>>>(deg, N);
    k_deg2<<<NSH * SUBG2, 256, 0, stream>>>(pbase, pedges, deg, rng);
    int nb1 = (N + 255) / 256;
    k_scan1<<<nb1, 256, 0, stream>>>(deg, sp, bsum, N);
    k_scan2<<<1, 512, 0, stream>>>(bsum, binc, nb1);
    k_scan3<<<nb1, 256, 0, stream>>>(sp, binc, rowptr, fill, N);
    k_scatter2<<<NSH * SUBG2, 256, 0, stream>>>(pbase, pedges, fill, eid,
                                                rng, N);

    // 3. per-dst softmax + weighted aggregation (one wave per node)
    k_agg<<<(N + 3) / 4, 256, 0, stream>>>(rowptr, eid, a_s, a_d, xlb, BIAS,
                                           OUT, N);
}

// Round 9
// 377.901 us; speedup vs baseline: 1.1770x; 1.0389x over previous
//
#include <hip/hip_runtime.h>

#define IN_CH  256
#define HCC    256   // HEADS*OUT_CH
#define HEADS  4
#define OUTC   64
#define NEG_SLOPE 0.2f

#define NSH    8      // dst-range shards == XCD count (blockIdx%8 ~ XCD)
#define NBLK   256    // partition blocks (each owns E/NBLK edge chunk)
#define SUBG2  64     // blocks per shard in scatter
#define SRC_BITS 18
#define SRC_MASK 0x3FFFF

using short8v = __attribute__((ext_vector_type(8))) short;
using f32x4   = __attribute__((ext_vector_type(4))) float;

__device__ __forceinline__ unsigned short f2bf(float f) {
    unsigned u = __float_as_uint(f);
    unsigned r = (u + 0x7fffu + ((u >> 16) & 1u)) >> 16;  // RNE
    return (unsigned short)r;
}
__device__ __forceinline__ float bf2f(unsigned short b) {
    return __uint_as_float((unsigned)b << 16);
}
__device__ __forceinline__ int shard_of(int dst, unsigned M) {
    unsigned s = (unsigned)(((unsigned long long)(unsigned)dst * M) >> 32);
    return (s >= NSH) ? (NSH - 1) : (int)s;
}

// ---------------------------------------------------------------------------
// Kernel 0: W [K=256][N=256] fp32 -> WT [N][K] bf16 (tiny, one-time)
// ---------------------------------------------------------------------------
__global__ void k_wt(const float* __restrict__ W,
                     unsigned short* __restrict__ WT) {
    int n = blockIdx.x;
    int k = threadIdx.x;
    WT[n * IN_CH + k] = f2bf(W[(size_t)k * HCC + n]);
}

// ---------------------------------------------------------------------------
// Kernel 1 (R6-proven): x_lin = X @ W via bf16 MFMA, BM=64, BN=256, BK=64,
// A and B staged in LDS. Attention logit dots fused in epilogue (wave==head).
// ---------------------------------------------------------------------------
__global__ __launch_bounds__(256) void k_gemm(const float* __restrict__ X,
                                              const unsigned short* __restrict__ WT,
                                              const float* __restrict__ ASRC,
                                              const float* __restrict__ ADST,
                                              unsigned short* __restrict__ XLB,
                                              float* __restrict__ a_s,
                                              float* __restrict__ a_d,
                                              int N) {
    __shared__ unsigned short Ats[64][72];   // [m][k]
    __shared__ unsigned short Bs[256][72];   // [n][k]
    const int tid = threadIdx.x;
    const int lane = tid & 63;
    const int wid = tid >> 6;
    const int m0 = blockIdx.x * 64;
    const int r16 = lane & 15;
    const int g = lane >> 4;

    f32x4 acc[4][4];
    const f32x4 z = {0.f, 0.f, 0.f, 0.f};
#pragma unroll
    for (int m = 0; m < 4; ++m)
#pragma unroll
        for (int n = 0; n < 4; ++n) acc[m][n] = z;

    for (int kb = 0; kb < IN_CH; kb += 64) {
#pragma unroll
        for (int it = 0; it < 4; ++it) {
            int v = tid + 256 * it;
            int row = v >> 4;
            int c4 = (v & 15) << 2;
            int gr = m0 + row;
            float4 av = make_float4(0.f, 0.f, 0.f, 0.f);
            if (gr < N) av = *(const float4*)(X + (size_t)gr * IN_CH + kb + c4);
            ushort4 ab;
            ab.x = f2bf(av.x); ab.y = f2bf(av.y);
            ab.z = f2bf(av.z); ab.w = f2bf(av.w);
            *(ushort4*)&Ats[row][c4] = ab;
        }
#pragma unroll
        for (int it = 0; it < 8; ++it) {
            int v = tid + 256 * it;
            int brow = v >> 3;
            int c8 = (v & 7) << 3;
            short8v bv = *(const short8v*)(WT + (size_t)brow * IN_CH + kb + c8);
            *(short8v*)&Bs[brow][c8] = bv;
        }
        __syncthreads();
#pragma unroll
        for (int ks = 0; ks < 2; ++ks) {
            short8v af[4], bf[4];
#pragma unroll
            for (int m = 0; m < 4; ++m)
                af[m] = *(const short8v*)&Ats[m * 16 + r16][ks * 32 + g * 8];
#pragma unroll
            for (int n = 0; n < 4; ++n)
                bf[n] = *(const short8v*)&Bs[wid * 64 + n * 16 + r16][ks * 32 + g * 8];
#pragma unroll
            for (int m = 0; m < 4; ++m)
#pragma unroll
                for (int n = 0; n < 4; ++n)
                    acc[m][n] = __builtin_amdgcn_mfma_f32_16x16x32_bf16(
                        af[m], bf[n], acc[m][n], 0, 0, 0);
        }
        __syncthreads();
    }

    const int h = wid;
    float asc[4], adc[4];
#pragma unroll
    for (int n = 0; n < 4; ++n) {
        asc[n] = ASRC[h * OUTC + n * 16 + r16];
        adc[n] = ADST[h * OUTC + n * 16 + r16];
    }

    // epilogue: D frag layout col=lane&15, row=(lane>>4)*4+j  [m89-verified]
#pragma unroll
    for (int m = 0; m < 4; ++m) {
#pragma unroll
        for (int j = 0; j < 4; ++j) {
            int row = m0 + m * 16 + g * 4 + j;
            float ds = 0.f, dd = 0.f;
#pragma unroll
            for (int n = 0; n < 4; ++n) {
                ds = fmaf(acc[m][n][j], asc[n], ds);
                dd = fmaf(acc[m][n][j], adc[n], dd);
            }
#pragma unroll
            for (int o = 1; o < 16; o <<= 1) {
                ds += __shfl_xor(ds, o);
                dd += __shfl_xor(dd, o);
            }
            if (row < N) {
                if (r16 == 0) {
                    a_s[(size_t)row * HEADS + h] = ds;
                    a_d[(size_t)row * HEADS + h] = dd;
                }
#pragma unroll
                for (int n = 0; n < 4; ++n) {
                    int col = wid * 64 + n * 16 + r16;
                    XLB[(size_t)row * HCC + col] = f2bf(acc[m][n][j]);
                }
            }
        }
    }
}

// ---------------------------------------------------------------------------
// CSR build v5: consolidated. One dst sweep feeds shard histogram AND degree
// histogram; self-loops folded into the scan (rowptr[i]=P_excl+i) and
// written by scan3b; shard-affine edge scatter over the partition.
// ---------------------------------------------------------------------------

// sweep 1: per-(block,shard) counts + global degree histogram
__global__ __launch_bounds__(256) void k_pcnt_deg(const int* __restrict__ ei,
                                                  int* __restrict__ pcnt2d,
                                                  int* __restrict__ deg,
                                                  int E, unsigned M) {
    __shared__ int h[NSH];
    int t = threadIdx.x;
    if (t < NSH) h[t] = 0;
    __syncthreads();
    int chunk = (E + NBLK - 1) / NBLK;
    int e0 = blockIdx.x * chunk;
    int e1 = e0 + chunk;
    if (e1 > E) e1 = E;
    for (int i = e0 + t; i < e1; i += 256) {
        int dst = ei[E + i];
        atomicAdd(&h[shard_of(dst, M)], 1);
        atomicAdd(&deg[dst], 1);
    }
    __syncthreads();
    if (t < NSH) pcnt2d[t * NBLK + blockIdx.x] = h[t];
}

// scan of the 2048 (shard-major) counts -> per-(block,shard) bases + pbase
__global__ __launch_bounds__(512) void k_pscan2(const int* __restrict__ pcnt2d,
                                                int* __restrict__ base2d,
                                                int* __restrict__ pbase,
                                                int E) {
    __shared__ int s[512];
    int t = threadIdx.x;
    int c[4];
    int sum = 0;
#pragma unroll
    for (int i = 0; i < 4; ++i) {
        c[i] = pcnt2d[t * 4 + i];
        sum += c[i];
    }
    s[t] = sum;
    __syncthreads();
    for (int off = 1; off < 512; off <<= 1) {
        int x = (t >= off) ? s[t - off] : 0;
        __syncthreads();
        s[t] += x;
        __syncthreads();
    }
    int run = s[t] - sum;  // exclusive
#pragma unroll
    for (int i = 0; i < 4; ++i) {
        int j = t * 4 + i;
        base2d[j] = run;
        if ((j & (NBLK - 1)) == 0) pbase[j / NBLK] = run;
        run += c[i];
    }
    if (t == 0) pbase[NSH] = E;
}

// sweep 2: write packed edges into exact block-private (block,shard) segments
__global__ __launch_bounds__(256) void k_part2(const int* __restrict__ ei,
                                               const int* __restrict__ base2d,
                                               unsigned* __restrict__ pedges,
                                               int E, unsigned M, int rng) {
    __shared__ int cur[NSH];
    int t = threadIdx.x;
    if (t < NSH) cur[t] = base2d[t * NBLK + blockIdx.x];
    __syncthreads();
    int chunk = (E + NBLK - 1) / NBLK;
    int e0 = blockIdx.x * chunk;
    int e1 = e0 + chunk;
    if (e1 > E) e1 = E;
    for (int i = e0 + t; i < e1; i += 256) {
        int src = ei[i];
        int dst = ei[E + i];
        int s = shard_of(dst, M);
        int pos = atomicAdd(&cur[s], 1);  // LDS atomic only
        pedges[pos] = ((unsigned)(dst - s * rng) << SRC_BITS) | (unsigned)src;
    }
}

__global__ void k_scan1(const int* __restrict__ in, int* __restrict__ sp,
                        int* __restrict__ bsum, int N) {
    __shared__ int s[256];
    int t = threadIdx.x;
    int i = blockIdx.x * 256 + t;
    int v = (i < N) ? in[i] : 0;
    s[t] = v;
    __syncthreads();
    for (int off = 1; off < 256; off <<= 1) {
        int x = (t >= off) ? s[t - off] : 0;
        __syncthreads();
        s[t] += x;
        __syncthreads();
    }
    if (i < N) sp[i] = s[t];
    if (t == 255) bsum[blockIdx.x] = s[255];
}

__global__ void k_scan2(const int* __restrict__ bsum, int* __restrict__ binc,
                        int nb) {
    __shared__ int s[512];
    int t = threadIdx.x;
    s[t] = (t < nb) ? bsum[t] : 0;
    __syncthreads();
    for (int off = 1; off < 512; off <<= 1) {
        int x = (t >= off) ? s[t - off] : 0;
        __syncthreads();
        s[t] += x;
        __syncthreads();
    }
    binc[t] = s[t];
}

// final scan step: rowptr (with +i self-loop offset), fill = rowptr+1, and
// the self-loop eid entries (near-sequential ascending writes).
__global__ void k_scan3b(const int* __restrict__ sp,
                         const int* __restrict__ binc,
                         const int* __restrict__ deg,
                         int* __restrict__ rowptr, int* __restrict__ fill,
                         int* __restrict__ eid, int N) {
    int b = blockIdx.x;
    int i = b * 256 + threadIdx.x;
    if (i >= N) return;
    int off = (b > 0) ? binc[b - 1] : 0;
    int v = sp[i] + off;             // inclusive edge-degree prefix
    rowptr[i + 1] = v + i + 1;       // +(i+1) self-loop slots
    if (i == 0) rowptr[0] = 0;
    int r0 = v - deg[i] + i;         // == rowptr[i]
    eid[r0] = i;                     // self-loop entry
    fill[i] = r0 + 1;
}

// shard-affine edge scatter over partitions (edges only)
__global__ __launch_bounds__(256) void k_scatter2b(const int* __restrict__ pbase,
                                                   const unsigned* __restrict__ pedges,
                                                   int* __restrict__ fill,
                                                   int* __restrict__ eid,
                                                   int rng) {
    int s = blockIdx.x & (NSH - 1);
    int sub = blockIdx.x >> 3;
    int lo = s * rng;
    int p0 = pbase[s];
    int cnt = pbase[s + 1] - p0;
    for (int j = sub * 256 + threadIdx.x; j < cnt; j += SUBG2 * 256) {
        unsigned pk = pedges[p0 + j];
        int dst = lo + (int)(pk >> SRC_BITS);
        int pos = atomicAdd(&fill[dst], 1);
        eid[pos] = (int)(pk & SRC_MASK);
    }
}

// ---------------------------------------------------------------------------
// Kernel 3: per-dst softmax + aggregation. One WAVE per node, lane owns 4
// channels. 8-deep edge unroll for gather MLP. No max subtraction (logits
// O(8), fp32 exp safe).
// ---------------------------------------------------------------------------
__global__ __launch_bounds__(256) void k_agg(const int* __restrict__ rowptr,
                                             const int* __restrict__ eid,
                                             const float* __restrict__ a_s,
                                             const float* __restrict__ a_d,
                                             const unsigned short* __restrict__ XLB,
                                             const float* __restrict__ BIAS,
                                             float* __restrict__ OUT, int N) {
    int wid = threadIdx.x >> 6;
    int lane = threadIdx.x & 63;
    int n = blockIdx.x * 4 + wid;
    if (n >= N) return;
    int h = lane >> 4;
    int s0 = rowptr[n];
    int s1 = rowptr[n + 1];
    float adn = a_d[(size_t)n * HEADS + h];
    float s = 0.f;
    float acc0 = 0.f, acc1 = 0.f, acc2 = 0.f, acc3 = 0.f;

    int e = s0;
    for (; e + 8 <= s1; e += 8) {
        int idx[8];
#pragma unroll
        for (int j = 0; j < 8; ++j) idx[j] = eid[e + j];
        float l[8];
#pragma unroll
        for (int j = 0; j < 8; ++j) l[j] = a_s[(size_t)idx[j] * HEADS + h] + adn;
        ushort4 xv[8];
#pragma unroll
        for (int j = 0; j < 8; ++j)
            xv[j] = *(const ushort4*)(XLB + (size_t)idx[j] * HCC + lane * 4);
#pragma unroll
        for (int j = 0; j < 8; ++j) {
            float lj = fmaxf(l[j], NEG_SLOPE * l[j]);
            float p = __expf(lj);
            s += p;
            acc0 = fmaf(p, bf2f(xv[j].x), acc0);
            acc1 = fmaf(p, bf2f(xv[j].y), acc1);
            acc2 = fmaf(p, bf2f(xv[j].z), acc2);
            acc3 = fmaf(p, bf2f(xv[j].w), acc3);
        }
    }
    for (; e + 4 <= s1; e += 4) {
        int idx[4];
#pragma unroll
        for (int j = 0; j < 4; ++j) idx[j] = eid[e + j];
        float l[4];
#pragma unroll
        for (int j = 0; j < 4; ++j) l[j] = a_s[(size_t)idx[j] * HEADS + h] + adn;
        ushort4 xv[4];
#pragma unroll
        for (int j = 0; j < 4; ++j)
            xv[j] = *(const ushort4*)(XLB + (size_t)idx[j] * HCC + lane * 4);
#pragma unroll
        for (int j = 0; j < 4; ++j) {
            float lj = fmaxf(l[j], NEG_SLOPE * l[j]);
            float p = __expf(lj);
            s += p;
            acc0 = fmaf(p, bf2f(xv[j].x), acc0);
            acc1 = fmaf(p, bf2f(xv[j].y), acc1);
            acc2 = fmaf(p, bf2f(xv[j].z), acc2);
            acc3 = fmaf(p, bf2f(xv[j].w), acc3);
        }
    }
    for (; e < s1; ++e) {
        int src = eid[e];
        float l = a_s[(size_t)src * HEADS + h] + adn;
        l = fmaxf(l, NEG_SLOPE * l);
        float p = __expf(l);
        ushort4 xv = *(const ushort4*)(XLB + (size_t)src * HCC + lane * 4);
        s += p;
        acc0 = fmaf(p, bf2f(xv.x), acc0);
        acc1 = fmaf(p, bf2f(xv.y), acc1);
        acc2 = fmaf(p, bf2f(xv.z), acc2);
        acc3 = fmaf(p, bf2f(xv.w), acc3);
    }

    float inv = 1.f / (s + 1e-16f);
    float4 b = *(const float4*)(BIAS + lane * 4);
    float4 o;
    o.x = acc0 * inv + b.x;
    o.y = acc1 * inv + b.y;
    o.z = acc2 * inv + b.z;
    o.w = acc3 * inv + b.w;
    *(float4*)(OUT + (size_t)n * HCC + lane * 4) = o;
}

// ---------------------------------------------------------------------------
extern "C" void kernel_launch(void* const* d_in, const int* in_sizes, int n_in,
                              void* d_out, int out_size, void* d_ws,
                              size_t ws_size, hipStream_t stream) {
    const float* X = (const float*)d_in[0];
    const int* EI = (const int*)d_in[1];
    const float* W = (const float*)d_in[2];
    const float* ASRC = (const float*)d_in[3];
    const float* ADST = (const float*)d_in[4];
    const float* BIAS = (const float*)d_in[5];
    float* OUT = (float*)d_out;

    const int N = in_sizes[0] / IN_CH;
    const int E = in_sizes[1] / 2;
    const int ET = E + N;
    const int rng = (N + NSH - 1) / NSH;
    const unsigned M = (unsigned)(((1ULL << 32) + rng - 1) / (unsigned)rng);

    // workspace layout (all 256B aligned)
    char* w = (char*)d_ws;
    auto align = [](size_t x) { return (x + 255) & ~(size_t)255; };
    size_t o = 0;
    unsigned short* xlb = (unsigned short*)(w + o); o += align((size_t)N * HCC * 2);
    unsigned short* wt = (unsigned short*)(w + o);  o += align((size_t)IN_CH * HCC * 2);
    float* a_s = (float*)(w + o); o += align((size_t)N * HEADS * 4);
    float* a_d = (float*)(w + o); o += align((size_t)N * HEADS * 4);
    int* deg = (int*)(w + o);     o += align((size_t)N * 4);
    int* rowptr = (int*)(w + o);  o += align((size_t)(N + 1) * 4);
    int* fill = (int*)(w + o);    o += align((size_t)N * 4);
    int* eid = (int*)(w + o);     o += align((size_t)ET * 4);
    unsigned* pedges = (unsigned*)(w + o); o += align((size_t)E * 4);
    int* sp = (int*)(w + o);      o += align((size_t)N * 4);
    int* bsum = (int*)(w + o);    o += align(512 * 4);
    int* binc = (int*)(w + o);    o += align(512 * 4);
    int* pcnt2d = (int*)(w + o);  o += align((size_t)NSH * NBLK * 4);
    int* base2d = (int*)(w + o);  o += align((size_t)NSH * NBLK * 4);
    int* pbase = (int*)(w + o);   o += align((NSH + 1) * 4);

    // 0. W -> WT (bf16, transposed)
    k_wt<<<HCC, IN_CH, 0, stream>>>(W, wt);

    // 1. linear projection -> bf16 x_lin + fused attention logits (MFMA)
    k_gemm<<<(N + 63) / 64, 256, 0, stream>>>(X, wt, ASRC, ADST, xlb, a_s,
                                              a_d, N);

    // 2. CSR build v5 (consolidated)
    hipMemsetAsync(deg, 0, (size_t)N * 4, stream);
    k_pcnt_deg<<<NBLK, 256, 0, stream>>>(EI, pcnt2d, deg, E, M);
    k_pscan2<<<1, 512, 0, stream>>>(pcnt2d, base2d, pbase, E);
    k_part2<<<NBLK, 256, 0, stream>>>(EI, base2d, pedges, E, M, rng);
    int nb1 = (N + 255) / 256;
    k_scan1<<<nb1, 256, 0, stream>>>(deg, sp, bsum, N);
    k_scan2<<<1, 512, 0, stream>>>(bsum, binc, nb1);
    k_scan3b<<<nb1, 256, 0, stream>>>(sp, binc, deg, rowptr, fill, eid, N);
    k_scatter2b<<<NSH * SUBG2, 256, 0, stream>>>(pbase, pedges, fill, eid,
                                                 rng);

    // 3. per-dst softmax + weighted aggregation (one wave per node)
    k_agg<<<(N + 3) / 4, 256, 0, stream>>>(rowptr, eid, a_s, a_d, xlb, BIAS,
                                           OUT, N);
}

// Round 10
// 338.608 us; speedup vs baseline: 1.3136x; 1.1160x over previous
//
#include <hip/hip_runtime.h>

#define IN_CH  256
#define HCC    256   // HEADS*OUT_CH
#define HEADS  4
#define OUTC   64
#define NEG_SLOPE 0.2f

#define NBUK   512    // dst buckets (rng = ceil(N/512) nodes each)
#define NBLK   64     // partition blocks (each owns E/NBLK edge chunk)
#define SRC_BITS 17
#define SRC_MASK 0x1FFFF

using short8v = __attribute__((ext_vector_type(8))) short;
using f32x4   = __attribute__((ext_vector_type(4))) float;

__device__ __forceinline__ unsigned short f2bf(float f) {
    unsigned u = __float_as_uint(f);
    unsigned r = (u + 0x7fffu + ((u >> 16) & 1u)) >> 16;  // RNE
    return (unsigned short)r;
}
__device__ __forceinline__ float bf2f(unsigned short b) {
    return __uint_as_float((unsigned)b << 16);
}
__device__ __forceinline__ int buk_of(int dst, unsigned M) {
    unsigned s = (unsigned)(((unsigned long long)(unsigned)dst * M) >> 32);
    return (s >= NBUK) ? (NBUK - 1) : (int)s;
}

// ---------------------------------------------------------------------------
// Kernel 0: W [K=256][N=256] fp32 -> WT [N][K] bf16 (tiny, one-time)
// ---------------------------------------------------------------------------
__global__ void k_wt(const float* __restrict__ W,
                     unsigned short* __restrict__ WT) {
    int n = blockIdx.x;
    int k = threadIdx.x;
    WT[n * IN_CH + k] = f2bf(W[(size_t)k * HCC + n]);
}

// ---------------------------------------------------------------------------
// Kernel 1 (R6-proven): x_lin = X @ W via bf16 MFMA, BM=64, BN=256, BK=64,
// A and B staged in LDS. Attention logit dots fused in epilogue (wave==head).
// ---------------------------------------------------------------------------
__global__ __launch_bounds__(256) void k_gemm(const float* __restrict__ X,
                                              const unsigned short* __restrict__ WT,
                                              const float* __restrict__ ASRC,
                                              const float* __restrict__ ADST,
                                              unsigned short* __restrict__ XLB,
                                              float* __restrict__ a_s,
                                              float* __restrict__ a_d,
                                              int N) {
    __shared__ unsigned short Ats[64][72];   // [m][k]
    __shared__ unsigned short Bs[256][72];   // [n][k]
    const int tid = threadIdx.x;
    const int lane = tid & 63;
    const int wid = tid >> 6;
    const int m0 = blockIdx.x * 64;
    const int r16 = lane & 15;
    const int g = lane >> 4;

    f32x4 acc[4][4];
    const f32x4 z = {0.f, 0.f, 0.f, 0.f};
#pragma unroll
    for (int m = 0; m < 4; ++m)
#pragma unroll
        for (int n = 0; n < 4; ++n) acc[m][n] = z;

    for (int kb = 0; kb < IN_CH; kb += 64) {
#pragma unroll
        for (int it = 0; it < 4; ++it) {
            int v = tid + 256 * it;
            int row = v >> 4;
            int c4 = (v & 15) << 2;
            int gr = m0 + row;
            float4 av = make_float4(0.f, 0.f, 0.f, 0.f);
            if (gr < N) av = *(const float4*)(X + (size_t)gr * IN_CH + kb + c4);
            ushort4 ab;
            ab.x = f2bf(av.x); ab.y = f2bf(av.y);
            ab.z = f2bf(av.z); ab.w = f2bf(av.w);
            *(ushort4*)&Ats[row][c4] = ab;
        }
#pragma unroll
        for (int it = 0; it < 8; ++it) {
            int v = tid + 256 * it;
            int brow = v >> 3;
            int c8 = (v & 7) << 3;
            short8v bv = *(const short8v*)(WT + (size_t)brow * IN_CH + kb + c8);
            *(short8v*)&Bs[brow][c8] = bv;
        }
        __syncthreads();
#pragma unroll
        for (int ks = 0; ks < 2; ++ks) {
            short8v af[4], bf[4];
#pragma unroll
            for (int m = 0; m < 4; ++m)
                af[m] = *(const short8v*)&Ats[m * 16 + r16][ks * 32 + g * 8];
#pragma unroll
            for (int n = 0; n < 4; ++n)
                bf[n] = *(const short8v*)&Bs[wid * 64 + n * 16 + r16][ks * 32 + g * 8];
#pragma unroll
            for (int m = 0; m < 4; ++m)
#pragma unroll
                for (int n = 0; n < 4; ++n)
                    acc[m][n] = __builtin_amdgcn_mfma_f32_16x16x32_bf16(
                        af[m], bf[n], acc[m][n], 0, 0, 0);
        }
        __syncthreads();
    }

    const int h = wid;
    float asc[4], adc[4];
#pragma unroll
    for (int n = 0; n < 4; ++n) {
        asc[n] = ASRC[h * OUTC + n * 16 + r16];
        adc[n] = ADST[h * OUTC + n * 16 + r16];
    }

    // epilogue: D frag layout col=lane&15, row=(lane>>4)*4+j  [m89-verified]
#pragma unroll
    for (int m = 0; m < 4; ++m) {
#pragma unroll
        for (int j = 0; j < 4; ++j) {
            int row = m0 + m * 16 + g * 4 + j;
            float ds = 0.f, dd = 0.f;
#pragma unroll
            for (int n = 0; n < 4; ++n) {
                ds = fmaf(acc[m][n][j], asc[n], ds);
                dd = fmaf(acc[m][n][j], adc[n], dd);
            }
#pragma unroll
            for (int o = 1; o < 16; o <<= 1) {
                ds += __shfl_xor(ds, o);
                dd += __shfl_xor(dd, o);
            }
            if (row < N) {
                if (r16 == 0) {
                    a_s[(size_t)row * HEADS + h] = ds;
                    a_d[(size_t)row * HEADS + h] = dd;
                }
#pragma unroll
                for (int n = 0; n < 4; ++n) {
                    int col = wid * 64 + n * 16 + r16;
                    XLB[(size_t)row * HCC + col] = f2bf(acc[m][n][j]);
                }
            }
        }
    }
}

// ---------------------------------------------------------------------------
// CSR build v6: deterministic fine-bucket partition + fully-local per-bucket
// finalize. No global atomics anywhere; no N-length scan chain.
// ---------------------------------------------------------------------------

// sweep 1: per-(bucket,block) counts via LDS histogram
__global__ __launch_bounds__(256) void k_pcnt(const int* __restrict__ ei,
                                              int* __restrict__ pcnt2d,
                                              int E, unsigned M) {
    __shared__ int h[NBUK];
    int t = threadIdx.x;
    for (int k = t; k < NBUK; k += 256) h[k] = 0;
    __syncthreads();
    int chunk = (E + NBLK - 1) / NBLK;
    int e0 = blockIdx.x * chunk;
    int e1 = e0 + chunk;
    if (e1 > E) e1 = E;
    for (int i = e0 + t; i < e1; i += 256)
        atomicAdd(&h[buk_of(ei[E + i], M)], 1);
    __syncthreads();
    for (int k = t; k < NBUK; k += 256)
        pcnt2d[k * NBLK + blockIdx.x] = h[k];
}

// scan of the NBUK*NBLK (bucket-major) counts -> base2d + per-bucket pbase
__global__ __launch_bounds__(1024) void k_pscan(const int* __restrict__ pcnt2d,
                                                int* __restrict__ base2d,
                                                int* __restrict__ pbase,
                                                int E) {
    __shared__ int s[1024];
    const int PT = (NBUK * NBLK) / 1024;  // 32 per thread
    int t = threadIdx.x;
    int c[PT];
    int sum = 0;
#pragma unroll
    for (int i = 0; i < PT; ++i) {
        c[i] = pcnt2d[t * PT + i];
        sum += c[i];
    }
    s[t] = sum;
    __syncthreads();
    for (int off = 1; off < 1024; off <<= 1) {
        int x = (t >= off) ? s[t - off] : 0;
        __syncthreads();
        s[t] += x;
        __syncthreads();
    }
    int run = s[t] - sum;  // exclusive
#pragma unroll
    for (int i = 0; i < PT; ++i) {
        int j = t * PT + i;
        base2d[j] = run;
        if ((j & (NBLK - 1)) == 0) pbase[j / NBLK] = run;
        run += c[i];
    }
    if (t == 0) pbase[NBUK] = E;
}

// sweep 2: write packed edges into exact block-private (bucket,block) segs
__global__ __launch_bounds__(256) void k_part2(const int* __restrict__ ei,
                                               const int* __restrict__ base2d,
                                               unsigned* __restrict__ pedges,
                                               int E, unsigned M, int rng) {
    __shared__ int cur[NBUK];
    int t = threadIdx.x;
    for (int k = t; k < NBUK; k += 256)
        cur[k] = base2d[k * NBLK + blockIdx.x];
    __syncthreads();
    int chunk = (E + NBLK - 1) / NBLK;
    int e0 = blockIdx.x * chunk;
    int e1 = e0 + chunk;
    if (e1 > E) e1 = E;
    for (int i = e0 + t; i < e1; i += 256) {
        int src = ei[i];
        int dst = ei[E + i];
        int s = buk_of(dst, M);
        int pos = atomicAdd(&cur[s], 1);  // LDS atomic only
        pedges[pos] = ((unsigned)(dst - s * rng) << SRC_BITS) | (unsigned)src;
    }
}

// per-bucket finalize: LDS histogram + scan -> rowptr, self-loops, eid.
// Bucket k's eid region = [pbase[k] + k*rng, ...) -- closed form, L2-local.
__global__ __launch_bounds__(256) void k_fin(const int* __restrict__ pbase,
                                             const unsigned* __restrict__ pedges,
                                             int* __restrict__ rowptr,
                                             int* __restrict__ eid,
                                             int N, int rng) {
    __shared__ int cntL[256];
    __shared__ int scanL[256];
    __shared__ int fillL[256];
    int k = blockIdx.x;
    int t = threadIdx.x;
    int lo = k * rng;
    if (lo >= N) return;
    int nloc = N - lo;
    if (nloc > rng) nloc = rng;
    int p0 = pbase[k];
    int cnt = pbase[k + 1] - p0;
    cntL[t] = 0;
    __syncthreads();
    for (int i = t; i < cnt; i += 256)
        atomicAdd(&cntL[pedges[p0 + i] >> SRC_BITS], 1);
    __syncthreads();
    int own = (t < nloc) ? cntL[t] + 1 : 0;  // +1 self-loop
    scanL[t] = own;
    __syncthreads();
    for (int off = 1; off < 256; off <<= 1) {
        int x = (t >= off) ? scanL[t - off] : 0;
        __syncthreads();
        scanL[t] += x;
        __syncthreads();
    }
    int excl = scanL[t] - own;
    int gbase = p0 + lo;  // edge prefix + self-loop prefix
    if (t < nloc) {
        rowptr[lo + t] = gbase + excl;
        if (lo + t == N - 1) rowptr[N] = gbase + excl + own;
        eid[gbase + excl] = lo + t;  // self-loop first
        fillL[t] = excl + 1;
    }
    __syncthreads();
    for (int i = t; i < cnt; i += 256) {
        unsigned pk = pedges[p0 + i];
        int dl = (int)(pk >> SRC_BITS);
        int pos = atomicAdd(&fillL[dl], 1);
        eid[gbase + pos] = (int)(pk & SRC_MASK);
    }
}

// ---------------------------------------------------------------------------
// Kernel 3: per-dst softmax + aggregation. One WAVE per node, lane owns 4
// channels. 8-deep edge unroll for gather MLP. No max subtraction (logits
// O(8), fp32 exp safe).
// ---------------------------------------------------------------------------
__global__ __launch_bounds__(256) void k_agg(const int* __restrict__ rowptr,
                                             const int* __restrict__ eid,
                                             const float* __restrict__ a_s,
                                             const float* __restrict__ a_d,
                                             const unsigned short* __restrict__ XLB,
                                             const float* __restrict__ BIAS,
                                             float* __restrict__ OUT, int N) {
    int wid = threadIdx.x >> 6;
    int lane = threadIdx.x & 63;
    int n = blockIdx.x * 4 + wid;
    if (n >= N) return;
    int h = lane >> 4;
    int s0 = rowptr[n];
    int s1 = rowptr[n + 1];
    float adn = a_d[(size_t)n * HEADS + h];
    float s = 0.f;
    float acc0 = 0.f, acc1 = 0.f, acc2 = 0.f, acc3 = 0.f;

    int e = s0;
    for (; e + 8 <= s1; e += 8) {
        int idx[8];
#pragma unroll
        for (int j = 0; j < 8; ++j) idx[j] = eid[e + j];
        float l[8];
#pragma unroll
        for (int j = 0; j < 8; ++j) l[j] = a_s[(size_t)idx[j] * HEADS + h] + adn;
        ushort4 xv[8];
#pragma unroll
        for (int j = 0; j < 8; ++j)
            xv[j] = *(const ushort4*)(XLB + (size_t)idx[j] * HCC + lane * 4);
#pragma unroll
        for (int j = 0; j < 8; ++j) {
            float lj = fmaxf(l[j], NEG_SLOPE * l[j]);
            float p = __expf(lj);
            s += p;
            acc0 = fmaf(p, bf2f(xv[j].x), acc0);
            acc1 = fmaf(p, bf2f(xv[j].y), acc1);
            acc2 = fmaf(p, bf2f(xv[j].z), acc2);
            acc3 = fmaf(p, bf2f(xv[j].w), acc3);
        }
    }
    for (; e + 4 <= s1; e += 4) {
        int idx[4];
#pragma unroll
        for (int j = 0; j < 4; ++j) idx[j] = eid[e + j];
        float l[4];
#pragma unroll
        for (int j = 0; j < 4; ++j) l[j] = a_s[(size_t)idx[j] * HEADS + h] + adn;
        ushort4 xv[4];
#pragma unroll
        for (int j = 0; j < 4; ++j)
            xv[j] = *(const ushort4*)(XLB + (size_t)idx[j] * HCC + lane * 4);
#pragma unroll
        for (int j = 0; j < 4; ++j) {
            float lj = fmaxf(l[j], NEG_SLOPE * l[j]);
            float p = __expf(lj);
            s += p;
            acc0 = fmaf(p, bf2f(xv[j].x), acc0);
            acc1 = fmaf(p, bf2f(xv[j].y), acc1);
            acc2 = fmaf(p, bf2f(xv[j].z), acc2);
            acc3 = fmaf(p, bf2f(xv[j].w), acc3);
        }
    }
    for (; e < s1; ++e) {
        int src = eid[e];
        float l = a_s[(size_t)src * HEADS + h] + adn;
        l = fmaxf(l, NEG_SLOPE * l);
        float p = __expf(l);
        ushort4 xv = *(const ushort4*)(XLB + (size_t)src * HCC + lane * 4);
        s += p;
        acc0 = fmaf(p, bf2f(xv.x), acc0);
        acc1 = fmaf(p, bf2f(xv.y), acc1);
        acc2 = fmaf(p, bf2f(xv.z), acc2);
        acc3 = fmaf(p, bf2f(xv.w), acc3);
    }

    float inv = 1.f / (s + 1e-16f);
    float4 b = *(const float4*)(BIAS + lane * 4);
    float4 o;
    o.x = acc0 * inv + b.x;
    o.y = acc1 * inv + b.y;
    o.z = acc2 * inv + b.z;
    o.w = acc3 * inv + b.w;
    *(float4*)(OUT + (size_t)n * HCC + lane * 4) = o;
}

// ---------------------------------------------------------------------------
extern "C" void kernel_launch(void* const* d_in, const int* in_sizes, int n_in,
                              void* d_out, int out_size, void* d_ws,
                              size_t ws_size, hipStream_t stream) {
    const float* X = (const float*)d_in[0];
    const int* EI = (const int*)d_in[1];
    const float* W = (const float*)d_in[2];
    const float* ASRC = (const float*)d_in[3];
    const float* ADST = (const float*)d_in[4];
    const float* BIAS = (const float*)d_in[5];
    float* OUT = (float*)d_out;

    const int N = in_sizes[0] / IN_CH;
    const int E = in_sizes[1] / 2;
    const int ET = E + N;
    const int rng = (N + NBUK - 1) / NBUK;
    const unsigned M = (unsigned)(((1ULL << 32) + rng - 1) / (unsigned)rng);

    // workspace layout (all 256B aligned)
    char* w = (char*)d_ws;
    auto align = [](size_t x) { return (x + 255) & ~(size_t)255; };
    size_t o = 0;
    unsigned short* xlb = (unsigned short*)(w + o); o += align((size_t)N * HCC * 2);
    unsigned short* wt = (unsigned short*)(w + o);  o += align((size_t)IN_CH * HCC * 2);
    float* a_s = (float*)(w + o); o += align((size_t)N * HEADS * 4);
    float* a_d = (float*)(w + o); o += align((size_t)N * HEADS * 4);
    int* rowptr = (int*)(w + o);  o += align((size_t)(N + 1) * 4);
    int* eid = (int*)(w + o);     o += align((size_t)ET * 4);
    unsigned* pedges = (unsigned*)(w + o); o += align((size_t)E * 4);
    int* pcnt2d = (int*)(w + o);  o += align((size_t)NBUK * NBLK * 4);
    int* base2d = (int*)(w + o);  o += align((size_t)NBUK * NBLK * 4);
    int* pbase = (int*)(w + o);   o += align((NBUK + 1) * 4);

    // 0. W -> WT (bf16, transposed)
    k_wt<<<HCC, IN_CH, 0, stream>>>(W, wt);

    // 1. linear projection -> bf16 x_lin + fused attention logits (MFMA)
    k_gemm<<<(N + 63) / 64, 256, 0, stream>>>(X, wt, ASRC, ADST, xlb, a_s,
                                              a_d, N);

    // 2. CSR build v6 (no global atomics, no N-scan)
    k_pcnt<<<NBLK, 256, 0, stream>>>(EI, pcnt2d, E, M);
    k_pscan<<<1, 1024, 0, stream>>>(pcnt2d, base2d, pbase, E);
    k_part2<<<NBLK, 256, 0, stream>>>(EI, base2d, pedges, E, M, rng);
    k_fin<<<NBUK, 256, 0, stream>>>(pbase, pedges, rowptr, eid, N, rng);

    // 3. per-dst softmax + weighted aggregation (one wave per node)
    k_agg<<<(N + 3) / 4, 256, 0, stream>>>(rowptr, eid, a_s, a_d, xlb, BIAS,
                                           OUT, N);
}

// Round 11
// 332.459 us; speedup vs baseline: 1.3379x; 1.0185x over previous
//
#include <hip/hip_runtime.h>

#define IN_CH  256
#define HCC    256   // HEADS*OUT_CH
#define HEADS  4
#define OUTC   64
#define NEG_SLOPE 0.2f

#define NBUK   512    // dst buckets (rng = ceil(N/512) nodes each)
#define NBLK   256    // partition blocks (each owns E/NBLK edge chunk)
#define SRC_BITS 17
#define SRC_MASK 0x1FFFF

using short8v = __attribute__((ext_vector_type(8))) short;
using f32x4   = __attribute__((ext_vector_type(4))) float;

__device__ __forceinline__ unsigned short f2bf(float f) {
    unsigned u = __float_as_uint(f);
    unsigned r = (u + 0x7fffu + ((u >> 16) & 1u)) >> 16;  // RNE
    return (unsigned short)r;
}
__device__ __forceinline__ float bf2f(unsigned short b) {
    return __uint_as_float((unsigned)b << 16);
}
__device__ __forceinline__ int buk_of(int dst, unsigned M) {
    unsigned s = (unsigned)(((unsigned long long)(unsigned)dst * M) >> 32);
    return (s >= NBUK) ? (NBUK - 1) : (int)s;
}

// ---------------------------------------------------------------------------
// Kernel 0: W [K=256][N=256] fp32 -> WT [N][K] bf16 (tiny, one-time)
// ---------------------------------------------------------------------------
__global__ void k_wt(const float* __restrict__ W,
                     unsigned short* __restrict__ WT) {
    int n = blockIdx.x;
    int k = threadIdx.x;
    WT[n * IN_CH + k] = f2bf(W[(size_t)k * HCC + n]);
}

// ---------------------------------------------------------------------------
// Kernel 1 (fused): heterogeneous grid.
//   blocks [0, ngemm):        R6-proven MFMA GEMM tile + fused att logits
//   blocks [ngemm, ngemm+NBLK): dst-bucket histogram (CSR sweep 1)
// Disjoint inputs/outputs; the histogram hides under the GEMM.
// ---------------------------------------------------------------------------
__global__ __launch_bounds__(256) void k_gemm_pcnt(
    const float* __restrict__ X, const unsigned short* __restrict__ WT,
    const float* __restrict__ ASRC, const float* __restrict__ ADST,
    unsigned short* __restrict__ XLB, float* __restrict__ a_s,
    float* __restrict__ a_d, int N, int ngemm,
    const int* __restrict__ ei, int* __restrict__ pcnt2d, int E, unsigned M) {
    __shared__ unsigned short Ats[64][72];   // [m][k]
    __shared__ unsigned short Bs[256][72];   // [n][k]
    __shared__ int hbuk[NBUK];

    if (blockIdx.x >= ngemm) {
        // ---- CSR sweep 1: per-(bucket,block) counts via LDS histogram ----
        int bid = blockIdx.x - ngemm;
        int t = threadIdx.x;
        for (int k = t; k < NBUK; k += 256) hbuk[k] = 0;
        __syncthreads();
        int chunk = (E + NBLK - 1) / NBLK;
        int e0 = bid * chunk;
        int e1 = e0 + chunk;
        if (e1 > E) e1 = E;
        for (int i = e0 + t; i < e1; i += 256)
            atomicAdd(&hbuk[buk_of(ei[E + i], M)], 1);
        __syncthreads();
        for (int k = t; k < NBUK; k += 256)
            pcnt2d[k * NBLK + bid] = hbuk[k];
        return;
    }

    // ---- GEMM tile ----
    const int tid = threadIdx.x;
    const int lane = tid & 63;
    const int wid = tid >> 6;
    const int m0 = blockIdx.x * 64;
    const int r16 = lane & 15;
    const int g = lane >> 4;

    f32x4 acc[4][4];
    const f32x4 z = {0.f, 0.f, 0.f, 0.f};
#pragma unroll
    for (int m = 0; m < 4; ++m)
#pragma unroll
        for (int n = 0; n < 4; ++n) acc[m][n] = z;

    for (int kb = 0; kb < IN_CH; kb += 64) {
#pragma unroll
        for (int it = 0; it < 4; ++it) {
            int v = tid + 256 * it;
            int row = v >> 4;
            int c4 = (v & 15) << 2;
            int gr = m0 + row;
            float4 av = make_float4(0.f, 0.f, 0.f, 0.f);
            if (gr < N) av = *(const float4*)(X + (size_t)gr * IN_CH + kb + c4);
            ushort4 ab;
            ab.x = f2bf(av.x); ab.y = f2bf(av.y);
            ab.z = f2bf(av.z); ab.w = f2bf(av.w);
            *(ushort4*)&Ats[row][c4] = ab;
        }
#pragma unroll
        for (int it = 0; it < 8; ++it) {
            int v = tid + 256 * it;
            int brow = v >> 3;
            int c8 = (v & 7) << 3;
            short8v bv = *(const short8v*)(WT + (size_t)brow * IN_CH + kb + c8);
            *(short8v*)&Bs[brow][c8] = bv;
        }
        __syncthreads();
#pragma unroll
        for (int ks = 0; ks < 2; ++ks) {
            short8v af[4], bf[4];
#pragma unroll
            for (int m = 0; m < 4; ++m)
                af[m] = *(const short8v*)&Ats[m * 16 + r16][ks * 32 + g * 8];
#pragma unroll
            for (int n = 0; n < 4; ++n)
                bf[n] = *(const short8v*)&Bs[wid * 64 + n * 16 + r16][ks * 32 + g * 8];
#pragma unroll
            for (int m = 0; m < 4; ++m)
#pragma unroll
                for (int n = 0; n < 4; ++n)
                    acc[m][n] = __builtin_amdgcn_mfma_f32_16x16x32_bf16(
                        af[m], bf[n], acc[m][n], 0, 0, 0);
        }
        __syncthreads();
    }

    const int h = wid;
    float asc[4], adc[4];
#pragma unroll
    for (int n = 0; n < 4; ++n) {
        asc[n] = ASRC[h * OUTC + n * 16 + r16];
        adc[n] = ADST[h * OUTC + n * 16 + r16];
    }

    // epilogue: D frag layout col=lane&15, row=(lane>>4)*4+j  [m89-verified]
#pragma unroll
    for (int m = 0; m < 4; ++m) {
#pragma unroll
        for (int j = 0; j < 4; ++j) {
            int row = m0 + m * 16 + g * 4 + j;
            float ds = 0.f, dd = 0.f;
#pragma unroll
            for (int n = 0; n < 4; ++n) {
                ds = fmaf(acc[m][n][j], asc[n], ds);
                dd = fmaf(acc[m][n][j], adc[n], dd);
            }
#pragma unroll
            for (int o = 1; o < 16; o <<= 1) {
                ds += __shfl_xor(ds, o);
                dd += __shfl_xor(dd, o);
            }
            if (row < N) {
                if (r16 == 0) {
                    a_s[(size_t)row * HEADS + h] = ds;
                    a_d[(size_t)row * HEADS + h] = dd;
                }
#pragma unroll
                for (int n = 0; n < 4; ++n) {
                    int col = wid * 64 + n * 16 + r16;
                    XLB[(size_t)row * HCC + col] = f2bf(acc[m][n][j]);
                }
            }
        }
    }
}

// ---------------------------------------------------------------------------
// CSR build v6.1: scan + partition + per-bucket finalize (all deterministic,
// no global atomics). NBLK=256 for full-machine parallelism.
// ---------------------------------------------------------------------------

// scan of the NBUK*NBLK (bucket-major) counts: two-pass per-thread (avoids
// a 128-deep register array -> scratch).
__global__ __launch_bounds__(1024) void k_pscan(const int* __restrict__ pcnt2d,
                                                int* __restrict__ base2d,
                                                int* __restrict__ pbase,
                                                int E) {
    __shared__ int s[1024];
    const int PT = (NBUK * NBLK) / 1024;  // 128 per thread
    int t = threadIdx.x;
    int sum = 0;
    for (int i = 0; i < PT; ++i) sum += pcnt2d[t * PT + i];
    s[t] = sum;
    __syncthreads();
    for (int off = 1; off < 1024; off <<= 1) {
        int x = (t >= off) ? s[t - off] : 0;
        __syncthreads();
        s[t] += x;
        __syncthreads();
    }
    int run = s[t] - sum;  // exclusive
    for (int i = 0; i < PT; ++i) {
        int j = t * PT + i;
        int c = pcnt2d[j];
        base2d[j] = run;
        if ((j & (NBLK - 1)) == 0) pbase[j / NBLK] = run;
        run += c;
    }
    if (t == 0) pbase[NBUK] = E;
}

// sweep 2: write packed edges into exact block-private (bucket,block) segs
__global__ __launch_bounds__(256) void k_part2(const int* __restrict__ ei,
                                               const int* __restrict__ base2d,
                                               unsigned* __restrict__ pedges,
                                               int E, unsigned M, int rng) {
    __shared__ int cur[NBUK];
    int t = threadIdx.x;
    for (int k = t; k < NBUK; k += 256)
        cur[k] = base2d[k * NBLK + blockIdx.x];
    __syncthreads();
    int chunk = (E + NBLK - 1) / NBLK;
    int e0 = blockIdx.x * chunk;
    int e1 = e0 + chunk;
    if (e1 > E) e1 = E;
    for (int i = e0 + t; i < e1; i += 256) {
        int src = ei[i];
        int dst = ei[E + i];
        int s = buk_of(dst, M);
        int pos = atomicAdd(&cur[s], 1);  // LDS atomic only
        pedges[pos] = ((unsigned)(dst - s * rng) << SRC_BITS) | (unsigned)src;
    }
}

// per-bucket finalize: LDS histogram + scan -> rowptr, self-loops, eid.
// Bucket k's eid region = [pbase[k] + k*rng, ...) -- closed form, L2-local.
__global__ __launch_bounds__(256) void k_fin(const int* __restrict__ pbase,
                                             const unsigned* __restrict__ pedges,
                                             int* __restrict__ rowptr,
                                             int* __restrict__ eid,
                                             int N, int rng) {
    __shared__ int cntL[256];
    __shared__ int scanL[256];
    __shared__ int fillL[256];
    int k = blockIdx.x;
    int t = threadIdx.x;
    int lo = k * rng;
    if (lo >= N) return;
    int nloc = N - lo;
    if (nloc > rng) nloc = rng;
    int p0 = pbase[k];
    int cnt = pbase[k + 1] - p0;
    cntL[t] = 0;
    __syncthreads();
    for (int i = t; i < cnt; i += 256)
        atomicAdd(&cntL[pedges[p0 + i] >> SRC_BITS], 1);
    __syncthreads();
    int own = (t < nloc) ? cntL[t] + 1 : 0;  // +1 self-loop
    scanL[t] = own;
    __syncthreads();
    for (int off = 1; off < 256; off <<= 1) {
        int x = (t >= off) ? scanL[t - off] : 0;
        __syncthreads();
        scanL[t] += x;
        __syncthreads();
    }
    int excl = scanL[t] - own;
    int gbase = p0 + lo;  // edge prefix + self-loop prefix
    if (t < nloc) {
        rowptr[lo + t] = gbase + excl;
        if (lo + t == N - 1) rowptr[N] = gbase + excl + own;
        eid[gbase + excl] = lo + t;  // self-loop first
        fillL[t] = excl + 1;
    }
    __syncthreads();
    for (int i = t; i < cnt; i += 256) {
        unsigned pk = pedges[p0 + i];
        int dl = (int)(pk >> SRC_BITS);
        int pos = atomicAdd(&fillL[dl], 1);
        eid[gbase + pos] = (int)(pk & SRC_MASK);
    }
}

// ---------------------------------------------------------------------------
// Kernel 3: per-dst softmax + aggregation. One WAVE per node, lane owns 4
// channels. 8-deep edge unroll for gather MLP. No max subtraction (logits
// O(8), fp32 exp safe).
// ---------------------------------------------------------------------------
__global__ __launch_bounds__(256) void k_agg(const int* __restrict__ rowptr,
                                             const int* __restrict__ eid,
                                             const float* __restrict__ a_s,
                                             const float* __restrict__ a_d,
                                             const unsigned short* __restrict__ XLB,
                                             const float* __restrict__ BIAS,
                                             float* __restrict__ OUT, int N) {
    int wid = threadIdx.x >> 6;
    int lane = threadIdx.x & 63;
    int n = blockIdx.x * 4 + wid;
    if (n >= N) return;
    int h = lane >> 4;
    int s0 = rowptr[n];
    int s1 = rowptr[n + 1];
    float adn = a_d[(size_t)n * HEADS + h];
    float s = 0.f;
    float acc0 = 0.f, acc1 = 0.f, acc2 = 0.f, acc3 = 0.f;

    int e = s0;
    for (; e + 8 <= s1; e += 8) {
        int idx[8];
#pragma unroll
        for (int j = 0; j < 8; ++j) idx[j] = eid[e + j];
        float l[8];
#pragma unroll
        for (int j = 0; j < 8; ++j) l[j] = a_s[(size_t)idx[j] * HEADS + h] + adn;
        ushort4 xv[8];
#pragma unroll
        for (int j = 0; j < 8; ++j)
            xv[j] = *(const ushort4*)(XLB + (size_t)idx[j] * HCC + lane * 4);
#pragma unroll
        for (int j = 0; j < 8; ++j) {
            float lj = fmaxf(l[j], NEG_SLOPE * l[j]);
            float p = __expf(lj);
            s += p;
            acc0 = fmaf(p, bf2f(xv[j].x), acc0);
            acc1 = fmaf(p, bf2f(xv[j].y), acc1);
            acc2 = fmaf(p, bf2f(xv[j].z), acc2);
            acc3 = fmaf(p, bf2f(xv[j].w), acc3);
        }
    }
    for (; e + 4 <= s1; e += 4) {
        int idx[4];
#pragma unroll
        for (int j = 0; j < 4; ++j) idx[j] = eid[e + j];
        float l[4];
#pragma unroll
        for (int j = 0; j < 4; ++j) l[j] = a_s[(size_t)idx[j] * HEADS + h] + adn;
        ushort4 xv[4];
#pragma unroll
        for (int j = 0; j < 4; ++j)
            xv[j] = *(const ushort4*)(XLB + (size_t)idx[j] * HCC + lane * 4);
#pragma unroll
        for (int j = 0; j < 4; ++j) {
            float lj = fmaxf(l[j], NEG_SLOPE * l[j]);
            float p = __expf(lj);
            s += p;
            acc0 = fmaf(p, bf2f(xv[j].x), acc0);
            acc1 = fmaf(p, bf2f(xv[j].y), acc1);
            acc2 = fmaf(p, bf2f(xv[j].z), acc2);
            acc3 = fmaf(p, bf2f(xv[j].w), acc3);
        }
    }
    for (; e < s1; ++e) {
        int src = eid[e];
        float l = a_s[(size_t)src * HEADS + h] + adn;
        l = fmaxf(l, NEG_SLOPE * l);
        float p = __expf(l);
        ushort4 xv = *(const ushort4*)(XLB + (size_t)src * HCC + lane * 4);
        s += p;
        acc0 = fmaf(p, bf2f(xv.x), acc0);
        acc1 = fmaf(p, bf2f(xv.y), acc1);
        acc2 = fmaf(p, bf2f(xv.z), acc2);
        acc3 = fmaf(p, bf2f(xv.w), acc3);
    }

    float inv = 1.f / (s + 1e-16f);
    float4 b = *(const float4*)(BIAS + lane * 4);
    float4 o;
    o.x = acc0 * inv + b.x;
    o.y = acc1 * inv + b.y;
    o.z = acc2 * inv + b.z;
    o.w = acc3 * inv + b.w;
    *(float4*)(OUT + (size_t)n * HCC + lane * 4) = o;
}

// ---------------------------------------------------------------------------
extern "C" void kernel_launch(void* const* d_in, const int* in_sizes, int n_in,
                              void* d_out, int out_size, void* d_ws,
                              size_t ws_size, hipStream_t stream) {
    const float* X = (const float*)d_in[0];
    const int* EI = (const int*)d_in[1];
    const float* W = (const float*)d_in[2];
    const float* ASRC = (const float*)d_in[3];
    const float* ADST = (const float*)d_in[4];
    const float* BIAS = (const float*)d_in[5];
    float* OUT = (float*)d_out;

    const int N = in_sizes[0] / IN_CH;
    const int E = in_sizes[1] / 2;
    const int ET = E + N;
    const int rng = (N + NBUK - 1) / NBUK;
    const unsigned M = (unsigned)(((1ULL << 32) + rng - 1) / (unsigned)rng);

    // workspace layout (all 256B aligned)
    char* w = (char*)d_ws;
    auto align = [](size_t x) { return (x + 255) & ~(size_t)255; };
    size_t o = 0;
    unsigned short* xlb = (unsigned short*)(w + o); o += align((size_t)N * HCC * 2);
    unsigned short* wt = (unsigned short*)(w + o);  o += align((size_t)IN_CH * HCC * 2);
    float* a_s = (float*)(w + o); o += align((size_t)N * HEADS * 4);
    float* a_d = (float*)(w + o); o += align((size_t)N * HEADS * 4);
    int* rowptr = (int*)(w + o);  o += align((size_t)(N + 1) * 4);
    int* eid = (int*)(w + o);     o += align((size_t)ET * 4);
    unsigned* pedges = (unsigned*)(w + o); o += align((size_t)E * 4);
    int* pcnt2d = (int*)(w + o);  o += align((size_t)NBUK * NBLK * 4);
    int* base2d = (int*)(w + o);  o += align((size_t)NBUK * NBLK * 4);
    int* pbase = (int*)(w + o);   o += align((NBUK + 1) * 4);

    // 0. W -> WT (bf16, transposed)
    k_wt<<<HCC, IN_CH, 0, stream>>>(W, wt);

    // 1. fused: MFMA GEMM (+att logits) || CSR bucket histogram
    int ngemm = (N + 63) / 64;
    k_gemm_pcnt<<<ngemm + NBLK, 256, 0, stream>>>(X, wt, ASRC, ADST, xlb,
                                                  a_s, a_d, N, ngemm, EI,
                                                  pcnt2d, E, M);

    // 2. CSR build v6.1
    k_pscan<<<1, 1024, 0, stream>>>(pcnt2d, base2d, pbase, E);
    k_part2<<<NBLK, 256, 0, stream>>>(EI, base2d, pedges, E, M, rng);
    k_fin<<<NBUK, 256, 0, stream>>>(pbase, pedges, rowptr, eid, N, rng);

    // 3. per-dst softmax + weighted aggregation (one wave per node)
    k_agg<<<(N + 3) / 4, 256, 0, stream>>>(rowptr, eid, a_s, a_d, xlb, BIAS,
                                           OUT, N);
}